// Round 8
// baseline (108.212 us; speedup 1.0000x reference)
//
#include <hip/hip_runtime.h>
#include <stdint.h>

#define N_ROWS 8192
#define DDIM   512

typedef __bf16 bf16_t;
typedef bf16_t bf16x8 __attribute__((ext_vector_type(8)));
typedef float  f32x4  __attribute__((ext_vector_type(4)));

#define MFMA16 __builtin_amdgcn_mfma_f32_16x16x32_bf16

// ---------------- f32 -> bf16 (RNE) convert, vectorized ----------------
__device__ inline uint16_t f2bf(float f) {
    uint32_t u = __float_as_uint(f);
    u += 0x7FFFu + ((u >> 16) & 1u);
    return (uint16_t)(u >> 16);
}

__global__ void convert_bf16(const float* __restrict__ a, const float* __restrict__ b,
                             uint16_t* __restrict__ abf, uint16_t* __restrict__ bbf) {
    const int quads = N_ROWS * DDIM / 4;
    const int stride = gridDim.x * blockDim.x;
    for (int i = blockIdx.x * blockDim.x + threadIdx.x; i < quads; i += stride) {
        float4 va = ((const float4*)a)[i];
        float4 vb = ((const float4*)b)[i];
        ushort4 ra, rb;
        ra.x = f2bf(va.x); ra.y = f2bf(va.y); ra.z = f2bf(va.z); ra.w = f2bf(va.w);
        rb.x = f2bf(vb.x); rb.y = f2bf(vb.y); rb.z = f2bf(vb.z); rb.w = f2bf(vb.w);
        ((ushort4*)abf)[i] = ra;
        ((ushort4*)bbf)[i] = rb;
    }
}

// ---------------- async global->LDS 16B stage ----------------
__device__ inline void stage16(const uint8_t* g, uint8_t* lds_wave_base) {
#if __has_builtin(__builtin_amdgcn_global_load_lds)
    __builtin_amdgcn_global_load_lds(
        (const __attribute__((address_space(1))) uint32_t*)g,
        (__attribute__((address_space(3))) uint32_t*)lds_wave_base, 16, 0, 0);
#else
    *(int4*)(lds_wave_base) = *(const int4*)g;
#endif
}

// ============================================================================
// m201-style 8-phase schedule: 256x256 tile, BK=64, 8 waves (2Mx4N), LDS dbuf
// 128 KB. Per K-tile: 4 phases, each = { issue reads for the NEXT quadrant
// (8 or 4 ds_read_b128 -> uniform, drains under THIS phase's MFMA), 2 stage16
// for tile t+2, barrier, setprio, 16 MFMA (one C-quadrant x K=64), setprio,
// barrier }. Counted vmcnt(4) once/tile at P1 (never 0 until tail).
// Register sets: a = {aA,aB} ping-pong across tiles + aC (within-tile a1);
// b = {bA (b0, spans P3(t-1)..P1(t)), bB (b1, within-tile)} — all static names.
// LDS: buf b at sh+b*65536: A 256x128B [0,32768), B [32768,65536); row r
// granule g at r*128+(g^(r&7))*16; staging source inverse-swizzled (rule #21).
// 2D-chunked XCD swizzle (proven: FETCH 24.7 MB). Read pattern = R5/R7's
// (measured 0 bank conflicts).
// ============================================================================
__global__ void __launch_bounds__(512, 2)
clip_gemm(const uint16_t* __restrict__ A, const uint16_t* __restrict__ B,
          const float* __restrict__ scale_p,
          float* __restrict__ rowsum, float* __restrict__ colsum,
          float* __restrict__ diag) {
    __shared__ __attribute__((aligned(16))) uint8_t sh[131072];

    const int t    = threadIdx.x;
    const int wave = t >> 6;
    const int lane = t & 63;
    const int wm   = wave >> 2;    // 0..1  (M half: 128 rows)
    const int wn   = wave & 3;     // 0..3  (N slice: 64 cols)
    const int lr   = lane & 15;
    const int lg   = lane >> 4;
    const int l7   = lane & 7;

    // 2D-chunked XCD swizzle: xcd owns 8bm x 16bn, bm-fastest.
    const int orig = blockIdx.x;               // 0..1023
    const int xcd  = orig & 7;
    const int idx  = orig >> 3;                // 0..127
    const int bm   = (xcd & 3) * 8  + (idx & 7);
    const int bn   = (xcd >> 2) * 16 + (idx >> 3);

    const float s     = *scale_p;
    const float shift = s - 64.0f;

    f32x4 acc[8][4];
#pragma unroll
    for (int i = 0; i < 8; ++i)
#pragma unroll
        for (int j = 0; j < 4; ++j)
#pragma unroll
            for (int r = 0; r < 4; ++r) acc[i][j][r] = 0.0f;

    // staging source (inverse-swizzled): thread t supplies row c*64+(t>>3),
    // granule (t&7)^((t>>3)&7) of K-tile kt.
    const int g16 = (((t & 7) ^ ((t >> 3) & 7)) << 4);
    const uint8_t* srcA = (const uint8_t*)A + (size_t)(bm * 256 + (t >> 3)) * 1024 + g16;
    const uint8_t* srcB = (const uint8_t*)B + (size_t)(bn * 256 + (t >> 3)) * 1024 + g16;
    uint8_t* dA = sh + wave * 1024;
    uint8_t* dB = sh + 32768 + wave * 1024;

#define STG_A(P, BS, c) stage16((P) + (size_t)(c) * 65536, dA + (BS) * 65536 + (c) * 8192)
#define STG_B(P, BS, c) stage16((P) + (size_t)(c) * 65536, dB + (BS) * 65536 + (c) * 8192)

    // fragment read offsets: chunk (kk*4+lg) ^ (lane&7)  [R5/R7: 0 conflicts]
    const int x0   = ((lg) ^ l7) << 4;        // kk=0
    const int x1   = ((4 | lg) ^ l7) << 4;    // kk=1
    const int aRow = (wm * 128 + lr) * 128;
    const int bRow = 32768 + (wn * 64 + lr) * 128;

    bf16x8 aA[2][4], aB[2][4], aC[2][4];   // [kk][i]
    bf16x8 bA[2][2], bB[2][2];             // [kk][j]

#define RD_AH(SET, BASE, IH) do {                                              \
        const uint8_t* _p = (const uint8_t*)(BASE) + aRow + (IH) * 8192;       \
        _Pragma("unroll")                                                      \
        for (int _i = 0; _i < 4; ++_i) {                                       \
            SET[0][_i] = *(const bf16x8*)(_p + _i * 2048 + x0);                \
            SET[1][_i] = *(const bf16x8*)(_p + _i * 2048 + x1);                \
        }                                                                      \
    } while (0)

#define RD_BH(SET, BASE, JH) do {                                              \
        const uint8_t* _p = (const uint8_t*)(BASE) + bRow + (JH) * 4096;       \
        _Pragma("unroll")                                                      \
        for (int _j = 0; _j < 2; ++_j) {                                       \
            SET[0][_j] = *(const bf16x8*)(_p + _j * 2048 + x0);                \
            SET[1][_j] = *(const bf16x8*)(_p + _j * 2048 + x1);                \
        }                                                                      \
    } while (0)

#define MMQ(IH, JH, AS, BS) do {                                               \
        _Pragma("unroll")                                                      \
        for (int _k = 0; _k < 2; ++_k)                                         \
        _Pragma("unroll")                                                      \
        for (int _i = 0; _i < 4; ++_i)                                         \
        _Pragma("unroll")                                                      \
        for (int _j = 0; _j < 2; ++_j)                                         \
            acc[(IH) * 4 + _i][(JH) * 2 + _j] =                                \
                MFMA16(AS[_k][_i], BS[_k][_j],                                 \
                       acc[(IH) * 4 + _i][(JH) * 2 + _j], 0, 0, 0);            \
    } while (0)

#define GATE_VM4  asm volatile("s_waitcnt vmcnt(4)" ::: "memory")
#define GATE_VM0  asm volatile("s_waitcnt vmcnt(0)" ::: "memory")
#define GATE_NONE ((void)0)

#define PH(RD, STG, GATE, IH, JH, AS, BS) do {                                 \
        RD;                                                                    \
        STG;                                                                   \
        GATE;                                                                  \
        __builtin_amdgcn_s_barrier();                                          \
        __builtin_amdgcn_s_setprio(1);                                         \
        MMQ(IH, JH, AS, BS);                                                   \
        __builtin_amdgcn_s_setprio(0);                                         \
        __builtin_amdgcn_s_barrier();                                          \
    } while (0)

    // TILE: BUF = this tile's LDS buffer, OBUF = next tile's; AP = a0 set,
    // AR = set receiving next tile's a0; PSA/PSB = staging src for tile t+2
    // (null in tail); BS = staging buffer select; NEXT = read next tile's
    // a0/b0 in P2/P3; GATE at P1.
#define TILE(BUF, OBUF, AP, AR, PSA, PSB, BS, NEXT, GATE)                      \
    PH(RD_AH(aC, BUF, 1),                                                      \
       do { if (PSA) { STG_A(PSA, BS, 0); STG_A(PSA, BS, 1); } } while (0),    \
       GATE_NONE, 0, 0, AP, bA);                                               \
    PH(RD_BH(bB, BUF, 1),                                                      \
       do { if (PSA) { STG_A(PSA, BS, 2); STG_A(PSA, BS, 3); } } while (0),    \
       GATE, 1, 0, aC, bA);                                                    \
    PH(do { if (NEXT) RD_AH(AR, OBUF, 0); } while (0),                         \
       do { if (PSB) { STG_B(PSB, BS, 0); STG_B(PSB, BS, 1); } } while (0),    \
       GATE_NONE, 0, 1, AP, bB);                                               \
    PH(do { if (NEXT) RD_BH(bA, OBUF, 0); } while (0),                         \
       do { if (PSB) { STG_B(PSB, BS, 2); STG_B(PSB, BS, 3); } } while (0),    \
       GATE_NONE, 1, 1, aC, bB)

    // ---------------- prologue: stage tiles 0,1; load Q0 of tile 0 ---------
#pragma unroll
    for (int c = 0; c < 4; ++c) { STG_A(srcA, 0, c); STG_B(srcB, 0, c); }
#pragma unroll
    for (int c = 0; c < 4; ++c) { STG_A(srcA + 128, 1, c); STG_B(srcB + 128, 1, c); }
    asm volatile("s_waitcnt vmcnt(8)" ::: "memory");   // tile 0 resident
    __builtin_amdgcn_s_barrier();
    RD_AH(aA, sh, 0);
    RD_BH(bA, sh, 0);

    // ---------------- main loop: tile pairs {0,1},{2,3},{4,5} --------------
    for (int p = 0; p < 3; ++p) {
        const uint8_t* puA = srcA + (size_t)(2 * p + 2) * 128;
        const uint8_t* puB = srcB + (size_t)(2 * p + 2) * 128;
        TILE(sh,         sh + 65536, aA, aB, puA,       puB,       0, 1, GATE_VM4);
        TILE(sh + 65536, sh,         aB, aA, puA + 128, puB + 128, 1, 1, GATE_VM4);
    }
    // ---------------- tail: tiles 6,7 (no staging) --------------------------
    TILE(sh,         sh + 65536, aA, aB, (const uint8_t*)0, (const uint8_t*)0, 0, 1, GATE_VM0);
    TILE(sh + 65536, sh,         aB, aA, (const uint8_t*)0, (const uint8_t*)0, 1, 0, GATE_NONE);

#undef TILE
#undef PH
#undef GATE_NONE
#undef GATE_VM0
#undef GATE_VM4
#undef MMQ
#undef RD_BH
#undef RD_AH
#undef STG_B
#undef STG_A

    // ---------------- epilogue: exp + reductions ----------------
    // D layout (16x16): col = lr, row = lg*4 + r  (verified R1/R5/R7).
    float cp[4] = {0.f, 0.f, 0.f, 0.f};
#pragma unroll
    for (int i = 0; i < 8; ++i) {
        float rp[4] = {0.f, 0.f, 0.f, 0.f};
#pragma unroll
        for (int j = 0; j < 4; ++j) {
#pragma unroll
            for (int r = 0; r < 4; ++r) {
                const float logit = s * acc[i][j][r];
                const float e = __expf(logit - shift);
                rp[r] += e;
                cp[j] += e;
                if (bm == bn) {
                    const int rr = wm * 128 + i * 16 + lg * 4 + r;
                    const int cc = wn * 64 + j * 16 + lr;
                    if (rr == cc) diag[bm * 256 + rr] = logit;
                }
            }
        }
#pragma unroll
        for (int r = 0; r < 4; ++r) {
            float v = rp[r];
            v += __shfl_xor(v, 1);
            v += __shfl_xor(v, 2);
            v += __shfl_xor(v, 4);
            v += __shfl_xor(v, 8);
            if (lr == 0)
                atomicAdd(&rowsum[bm * 256 + wm * 128 + i * 16 + lg * 4 + r], v);
        }
    }
#pragma unroll
    for (int j = 0; j < 4; ++j) {
        float v = cp[j];
        v += __shfl_xor(v, 16);
        v += __shfl_xor(v, 32);
        if (lg == 0)
            atomicAdd(&colsum[bn * 256 + wn * 64 + j * 16 + lr], v);
    }
}

// ---------------- final reduce: loss scalar (parallel) ----------------
__global__ void clip_finalize(const float* __restrict__ rowsum, const float* __restrict__ colsum,
                              const float* __restrict__ diag, const float* __restrict__ scale_p,
                              float* __restrict__ out) {
    __shared__ float red[4];
    const float s = *scale_p;
    const float shift = s - 64.0f;
    const int i = blockIdx.x * 256 + threadIdx.x;   // grid 32 x 256 = 8192
    float acc = logf(rowsum[i]) + logf(colsum[i]) + 2.f * shift - 2.f * diag[i];
#pragma unroll
    for (int m = 1; m < 64; m <<= 1) acc += __shfl_xor(acc, m);
    const int wave = threadIdx.x >> 6;
    const int lane = threadIdx.x & 63;
    if (lane == 0) red[wave] = acc;
    __syncthreads();
    if (threadIdx.x == 0) {
        atomicAdd(out, (red[0] + red[1] + red[2] + red[3]) / (2.0f * N_ROWS));
    }
}

extern "C" void kernel_launch(void* const* d_in, const int* in_sizes, int n_in,
                              void* d_out, int out_size, void* d_ws, size_t ws_size,
                              hipStream_t stream) {
    const float* img     = (const float*)d_in[0];
    const float* txt     = (const float*)d_in[1];
    const float* scale_p = (const float*)d_in[2];

    uint8_t* ws = (uint8_t*)d_ws;
    uint16_t* Abf   = (uint16_t*)ws;                                  // 8 MB
    uint16_t* Bbf   = (uint16_t*)(ws + (size_t)8 * 1024 * 1024);      // 8 MB
    float*    rowsum = (float*)(ws + (size_t)16 * 1024 * 1024);       // 32 KB
    float*    colsum = rowsum + N_ROWS;                               // 32 KB
    float*    diag   = colsum + N_ROWS;                               // 32 KB
    float*    out    = (float*)d_out;

    hipMemsetAsync(rowsum, 0, 2 * N_ROWS * sizeof(float), stream);
    hipMemsetAsync(out, 0, sizeof(float), stream);
    convert_bf16<<<1024, 256, 0, stream>>>(img, txt, Abf, Bbf);
    clip_gemm<<<1024, 512, 0, stream>>>(Abf, Bbf, scale_p, rowsum, colsum, diag);
    clip_finalize<<<32, 256, 0, stream>>>(rowsum, colsum, diag, scale_p, out);
}